// Round 7
// baseline (257.543 us; speedup 1.0000x reference)
//
#include <hip/hip_runtime.h>
#include <hip/hip_bf16.h>

// LoKr: out = x @ kron(w1, a@b).T * S, factored into 3 small GEMMs.
// x view: [65536 A-rows (pos*8+ij) x 512 il], b: [64 r x 512 il],
// a: [512 ok x 64 r], out row (pos*8+oi) x 512 ok.
//
// R9->R10: per-wave MLP experiment, de-risked retry (R9 container died
// twice; its full stage-3 af[4][4] hoist pushed peak demand to ~250 VGPR,
// at the 256 cap -> allocator blowup risk). Core experiment unchanged:
// five structures all pinned at 92-98us with VGPR 44-88 (allocator
// serialized every prefetch -> depth<=1 pipeline -> latency-serial waves
// regardless of structure). Now launch_bounds(128,2) (256-VGPR cap) and
// stage-1 issues ALL 32 x float4 loads up front (xb[8][4], ~128 VGPR of
// x in flight). Stage 3 = R8's per-group a-loads (L2-resident, hoisting
// them all bought nothing). Store path = R8 LDS bounce + linear NT.

typedef __attribute__((ext_vector_type(4))) float f32x4;
typedef __attribute__((ext_vector_type(8))) short s16x8;

__device__ inline unsigned short f2bf(float f) {
    unsigned u = __float_as_uint(f);
    u += 0x7FFF + ((u >> 16) & 1);   // round-to-nearest-even
    return (unsigned short)(u >> 16);
}

__device__ inline s16x8 pack8(float4 lo, float4 hi) {
    s16x8 h;
    h[0] = (short)f2bf(lo.x); h[1] = (short)f2bf(lo.y);
    h[2] = (short)f2bf(lo.z); h[3] = (short)f2bf(lo.w);
    h[4] = (short)f2bf(hi.x); h[5] = (short)f2bf(hi.y);
    h[6] = (short)f2bf(hi.z); h[7] = (short)f2bf(hi.w);
    return h;
}

// Precompute: b -> bf16 [64][512] (row=r, col=il), a -> bf16 [512][64]
// (row=ok, col=r), w1s = w1 * (1/64). Into d_ws (re-poisoned each call).
__global__ void lokr_pre(const float* __restrict__ w1,
                         const float* __restrict__ a,
                         const float* __restrict__ b,
                         unsigned short* __restrict__ b_bf,
                         unsigned short* __restrict__ a_bf,
                         float* __restrict__ w1s) {
    int i = blockIdx.x * 256 + threadIdx.x;
    if (i < 32768) {
        b_bf[i] = f2bf(b[i]);
        a_bf[i] = f2bf(a[i]);
    }
    if (i < 64) w1s[i] = w1[i] * (1.0f / 64.0f);
}

#define LSTR 72    // vs row stride in shorts (64 + 8 pad)
#define CSTR 132   // ct row stride in floats (128 + 4 pad, keeps 16B align)

__global__ __launch_bounds__(128, 2) void lokr_main(
    const float* __restrict__ x,
    const unsigned short* __restrict__ b_bf,
    const unsigned short* __restrict__ a_bf,
    const float* __restrict__ w1s,
    float* __restrict__ out)
{
    // Aliased scratch: vs (stage-2 v, 32x72 shorts = 4.6KB) then ct
    // (stage-3 C bounce, 32x132 f32 = 16.9KB). Barriers separate uses.
    __shared__ __attribute__((aligned(16))) unsigned char smem[32 * CSTR * 4];
    __shared__ float w1_s[64];
    unsigned short* vs = (unsigned short*)smem;
    float*          ct = (float*)smem;

    const int t    = threadIdx.x;
    const int wave = t >> 6;
    const int lane = t & 63;
    const int col  = lane & 15;   // MFMA: A row / B col / C col
    const int quad = lane >> 4;
    const long rowbase = (long)blockIdx.x * 32;
    const long wrow    = rowbase + wave * 16;   // this wave's 16 A-rows

    // both waves write identical values -> benign race, no barrier needed
    w1_s[lane] = w1s[lane];

    // Lane's A-fragment source: row wrow+col, k-chunk quad*8 (+32 for a1).
    const float* xw = x + (wrow + col) * 512 + quad * 8;
    // b-frag source: r = rt*16+col, k = s*64 + quad*8 (+32).
    const unsigned short* bw = b_bf + col * 512 + quad * 8;

    // ---- stage 1: T[16 rows x 64 r]; ALL x loads issued up front ----
    float4 xb[8][4];
    #pragma unroll
    for (int s = 0; s < 8; ++s) {
        const float* xg = xw + s * 64;
        xb[s][0] = *(const float4*)(xg);
        xb[s][1] = *(const float4*)(xg + 4);
        xb[s][2] = *(const float4*)(xg + 32);
        xb[s][3] = *(const float4*)(xg + 36);
    }

    f32x4 acc[4];
    #pragma unroll
    for (int rt = 0; rt < 4; ++rt) acc[rt] = (f32x4){0.f, 0.f, 0.f, 0.f};

    s16x8 bc0[4], bc1[4];
    #pragma unroll
    for (int rt = 0; rt < 4; ++rt) {
        bc0[rt] = *(const s16x8*)(bw + rt * 8192);
        bc1[rt] = *(const s16x8*)(bw + rt * 8192 + 32);
    }

    #pragma unroll
    for (int s = 0; s < 8; ++s) {
        // b-frags for slab s+1 issued before consuming slab s (L2-resident)
        s16x8 bn0[4], bn1[4];
        if (s < 7) {
            #pragma unroll
            for (int rt = 0; rt < 4; ++rt) {
                bn0[rt] = *(const s16x8*)(bw + rt * 8192 + (s + 1) * 64);
                bn1[rt] = *(const s16x8*)(bw + rt * 8192 + (s + 1) * 64 + 32);
            }
        }
        s16x8 a0 = pack8(xb[s][0], xb[s][1]);
        s16x8 a1 = pack8(xb[s][2], xb[s][3]);
        #pragma unroll
        for (int rt = 0; rt < 4; ++rt) {
            acc[rt] = __builtin_amdgcn_mfma_f32_16x16x32_bf16(a0, bc0[rt], acc[rt], 0, 0, 0);
            acc[rt] = __builtin_amdgcn_mfma_f32_16x16x32_bf16(a1, bc1[rt], acc[rt], 0, 0, 0);
        }
        if (s < 7) {
            #pragma unroll
            for (int rt = 0; rt < 4; ++rt) { bc0[rt] = bn0[rt]; bc1[rt] = bn1[rt]; }
        }
    }

    // ---- stage 2: mix ij->oi with w1, write v (bf16) to LDS ----
    // acc[rt]: T row_local = quad*4+reg (16 rows = 2 positions x 8 ij),
    // r = rt*16+col. p = quad>>1; shfl_xor(16) exchanges the complementary
    // ij half; quad&1 splits the 8 oi.
    const int p   = quad >> 1;
    const int oib = (quad & 1) * 4;
    #pragma unroll
    for (int rt = 0; rt < 4; ++rt) {
        float own[4], oth[4], tij[8];
        #pragma unroll
        for (int j = 0; j < 4; ++j) own[j] = acc[rt][j];
        #pragma unroll
        for (int j = 0; j < 4; ++j) oth[j] = __shfl_xor(own[j], 16);
        if ((quad & 1) == 0) {
            #pragma unroll
            for (int j = 0; j < 4; ++j) { tij[j] = own[j]; tij[4 + j] = oth[j]; }
        } else {
            #pragma unroll
            for (int j = 0; j < 4; ++j) { tij[j] = oth[j]; tij[4 + j] = own[j]; }
        }
        #pragma unroll
        for (int oo = 0; oo < 4; ++oo) {
            float v = 0.f;
            #pragma unroll
            for (int j = 0; j < 8; ++j) v += w1_s[(oib + oo) * 8 + j] * tij[j];
            vs[(wave * 16 + p * 8 + oib + oo) * LSTR + rt * 16 + col] = f2bf(v);
        }
    }
    __syncthreads();   // vs complete -> va loads

    // ---- stage 3: out[32 x 512] = v[32 x 64] @ a^T, 4 ok-groups of 128.
    // Swapped operands: C[ok][xrow]. Per-group a-loads hoisted above the
    // group's MFMAs. C bounces through ct, streamed as linear NT.
    s16x8 va[2][2];
    #pragma unroll
    for (int m = 0; m < 2; ++m) {
        const unsigned short* vp = &vs[(m * 16 + col) * LSTR + quad * 8];
        va[m][0] = *(const s16x8*)(vp);
        va[m][1] = *(const s16x8*)(vp + 32);
    }
    __syncthreads();   // va reads drained before ct overwrites vs (alias)

    const int srow = t >> 5;          // 0..3: store-row within 4-row band
    const int scol = (t & 31) * 4;    // 0..124: float col within 128-group

    for (int g = 0; g < 4; ++g) {
        s16x8 af0[4], af1[4];
        #pragma unroll
        for (int j = 0; j < 4; ++j) {
            const unsigned short* ag =
                a_bf + (g * 128 + wave * 64 + j * 16 + col) * 64 + quad * 8;
            af0[j] = *(const s16x8*)(ag);
            af1[j] = *(const s16x8*)(ag + 32);
        }
        #pragma unroll
        for (int j = 0; j < 4; ++j) {
            const int okl = wave * 64 + j * 16;   // local ok base
            #pragma unroll
            for (int m = 0; m < 2; ++m) {
                f32x4 c = {0.f, 0.f, 0.f, 0.f};
                c = __builtin_amdgcn_mfma_f32_16x16x32_bf16(af0[j], va[m][0], c, 0, 0, 0);
                c = __builtin_amdgcn_mfma_f32_16x16x32_bf16(af1[j], va[m][1], c, 0, 0, 0);
                // C row = okl + quad*4 + reg (local ok), C col = m*16+col
                *(f32x4*)&ct[(m * 16 + col) * CSTR + okl + quad * 4] = c;
            }
        }
        __syncthreads();   // ct complete
        // stream 16KB: 8 instrs x 128 thr x 16B; each instr = 4 rows x
        // 512B aligned contiguous chunks -> full-line NT write-combining.
        float* og = out + (rowbase + srow) * 512 + g * 128 + scol;
        #pragma unroll
        for (int i = 0; i < 8; ++i) {
            f32x4 cv = *(const f32x4*)&ct[(i * 4 + srow) * CSTR + scol];
            __builtin_nontemporal_store(cv, (f32x4*)(og + (long)i * 4 * 512));
        }
        if (g < 3) __syncthreads();   // before next group's ct overwrite
    }
}

extern "C" void kernel_launch(void* const* d_in, const int* in_sizes, int n_in,
                              void* d_out, int out_size, void* d_ws, size_t ws_size,
                              hipStream_t stream) {
    const float* x  = (const float*)d_in[0];  // [4,2048,4096]
    const float* w1 = (const float*)d_in[1];  // [8,8]
    const float* a  = (const float*)d_in[2];  // [512,64]
    const float* b  = (const float*)d_in[3];  // [64,512]

    unsigned short* b_bf = (unsigned short*)d_ws;          // 64 KB
    unsigned short* a_bf = b_bf + 32768;                   // 64 KB
    float*          w1s  = (float*)(a_bf + 32768);         // 256 B

    lokr_pre<<<128, 256, 0, stream>>>(w1, a, b, b_bf, a_bf, w1s);
    lokr_main<<<2048, 128, 0, stream>>>(x, b_bf, a_bf, w1s, (float*)d_out);
}